// Round 13
// baseline (76.320 us; speedup 1.0000x reference)
//
#include <hip/hip_runtime.h>

// Problem constants: B=8, S=1024, E=128, H=32, DK=4.
constexpr int kS = 1024;

typedef __fp16 fp16x2 __attribute__((ext_vector_type(2)));  // storage only
typedef _Float16 half4v __attribute__((ext_vector_type(4)));
typedef _Float16 half8v __attribute__((ext_vector_type(8)));
typedef float float4v __attribute__((ext_vector_type(4)));
typedef float float16v __attribute__((ext_vector_type(16)));

// ---------------------------------------------------------------------------
// K1: quantum encoder (analytic collapse, verified R1-R11).
// z0=c1c2c3, z1=c0c1, z2=c0c1c2, z3=c0c1c2c3, c_w=cos(x_w + theta_w).
// h16[bh][s][d] = f16(0.25*z_d); attn duplicates dims 4x across 16 k-slots
// -> ST = 4*(1/16)*z_q.z_k = q.k/4 = u in [-1,1] exactly.
// hvq[bh][kb(32)][chunk(2)][row(8)][hi(2)][j(8)] f16 (V^T fragments):
//   key = kb*32 + chunk*16 + kappa(hi,j), kappa = (j&3) + 8*(j>>2) + 4*hi.
//   rows 0-3 = z_d, row 4 = 1.0 (denominator), rows 5-7 = 0.0.
// R12 LESSON: rows 5-7 were "don't-care" (never written) -> kernel output
// depended on ws poison state -> post-timing divergence. NO don't-care
// state: every byte the kernel reads is written every call.
// ---------------------------------------------------------------------------
__global__ __launch_bounds__(256) void qenc_kernel(
    const float4* __restrict__ x4, const float* __restrict__ qp,
    uint2* __restrict__ h16u, ushort* __restrict__ hvq,
    uint2* __restrict__ hvq2) {
  int idx = blockIdx.x * 256 + threadIdx.x;
  float4 a = x4[idx];
  float c0 = cosf(a.x + qp[0]);
  float c1 = cosf(a.y + qp[1]);
  float c2 = cosf(a.z + qp[2]);
  float c3 = cosf(a.w + qp[3]);
  float z1 = c0 * c1;
  float z2 = z1 * c2;
  float z3 = z2 * c3;
  float z0 = c1 * c2 * c3;
  // Q/K copy: 0.25*z (4x slot duplication in attn -> ST = q.k/4)
  union { half4v h; uint2 u; } q;
  q.h.x = (_Float16)(z0 * 0.25f);
  q.h.y = (_Float16)(z1 * 0.25f);
  q.h.z = (_Float16)(z2 * 0.25f);
  q.h.w = (_Float16)(z3 * 0.25f);
  // V copy: unscaled
  union { half4v h; ushort4 us; } v;
  v.h.x = (_Float16)z0;
  v.h.y = (_Float16)z1;
  v.h.z = (_Float16)z2;
  v.h.w = (_Float16)z3;
  int b = idx >> 15;
  int s = (idx >> 5) & (kS - 1);
  int head = idx & 31;
  int bh = b * 32 + head;
  h16u[(bh << 10) + s] = q.u;
  // V^T scatter: key s -> (kb, chunk, hi, j)
  int kb = s >> 5, kk = s & 31;
  int chunk = (kk >> 4) & 1, kk4 = kk & 15;
  int hi = (kk4 >> 2) & 1;
  int j = (kk4 & 3) + ((kk4 >> 3) << 2);
  int base = (bh << 13) + (kb << 8) + (chunk << 7) + (hi << 3) + j;
  hvq[base + 0] = v.us.x;   // row 0
  hvq[base + 16] = v.us.y;  // row 1
  hvq[base + 32] = v.us.z;  // row 2
  hvq[base + 48] = v.us.w;  // row 3
  // Rows 4-7 of every (bh, kb, chunk): region uint2[16..31] within the
  // chunk's 32 uint2. 64 chunks x 16 uint2 = 1024 per bh = 1 per thread.
  // off2 0-3 -> row 4 = 1.0 pairs; off2 4-15 -> rows 5-7 = 0.
  {
    int t = s;                 // 0..1023
    int chunk_id = t >> 4;     // (kb*2+chunk) 0..63
    int off2 = t & 15;         // uint2 within rows 4-7 region
    uint fill = (off2 < 4) ? 0x3C003C00u : 0u;
    hvq2[(bh << 11) + (chunk_id << 5) + 16 + off2] = make_uint2(fill, fill);
  }
}

// Force VOP3P packed-f16 fma: hipcc scalarizes ext-vector f16 arithmetic
// (R10/R11: identical scalarized codegen for __fp16 and _Float16).
// VOP3P takes no literals -> coeffs live in VGPRs. "=&v" early-clobber so
// the dest can never alias a live input/coefficient register.
#define PKFMA(D, A, B, Cc) \
  asm("v_pk_fma_f16 %0, %1, %2, %3" : "=&v"(D) : "v"(A), "v"(B), "v"(Cc))

// ---------------------------------------------------------------------------
// K2: fused attention, exp-free. mfma_f32_32x32x16_f16; one wave = (bh, 32 q).
// QK^T: dims duplicated 4x across 16 k-slots on both operands (0.25*z stored)
// -> ST = u = q.k/4 in [-1,1] exactly.
// P = e^{2u} via degree-6 Chebyshev Horner in asm v_pk_fma_f16 (48 ops/iter
// ~= 96 cyc, replacing 16 v_exp_f32 ~= 256 cyc / R11's ~400 scalarized).
// ST C/D (m74/m101): col=lane&31=q, regs 0-7 = keys kappa(hi,j) chunk 0,
// regs 8-15 = chunk 1 -> PV B-frag for chunk c = poly(cvt(st[8c..8c+7])).
// Both P and V place key 16c+kappa(hi,j) at slot (j,hi): contraction pairs
// matching keys for any hw slot->k bijection. PV A-frag = hvq rows (r&7):
// rows 0-3 V data, row 4 ones (denominator in acc reg0 of hi lanes),
// rows 5-7 zeros (state-independence, R12 lesson).
// ---------------------------------------------------------------------------
__global__ __launch_bounds__(256) void attn_kernel(
    const _Float16* __restrict__ h16, const _Float16* __restrict__ hvq,
    uint2* __restrict__ o16u2) {
  const int lane = threadIdx.x & 63;
  const int wv = threadIdx.x >> 6;
  const int job = blockIdx.x * 4 + wv;
  const int bh = job >> 5;
  const int q0 = (job & 31) << 5;
  const int r = lane & 31;
  const int hi = lane >> 5;

  const uint2* __restrict__ hb2 = (const uint2*)(h16) + (bh << 10);
  const uint4* __restrict__ vb4 = (const uint4*)(hvq) + (bh << 10);

  // e^{2u}, u in [-1,1]: deg-6 Chebyshev, coeffs pre-rounded to f16 pairs.
  // {1.0, 2.003906, 2.001953, 1.308594, 0.657227, 0.314453, 0.102417}
  const uint kC0 = 0x3C003C00u;
  const uint kC1 = 0x40024002u;
  const uint kC2 = 0x40014001u;
  const uint kC3 = 0x3D3C3D3Cu;
  const uint kC4 = 0x39423942u;
  const uint kC5 = 0x35083508u;
  const uint kC6 = 0x2E8E2E8Eu;

  union U4H { uint4 u; half8v h; };
  U4H uq;
  {
    uint2 qv = hb2[q0 + r];
    uq.u.x = qv.x; uq.u.y = qv.y; uq.u.z = qv.x; uq.u.w = qv.y;
  }

  const int vbase = ((r & 7) << 1) + hi;  // uint4 idx within kb: row*2 + hi

  float16v acc = {};
  const float16v zero = {};

#pragma unroll 2
  for (int k0 = 0; k0 < kS; k0 += 32) {
    U4H uk;
    {
      uint2 kv = hb2[k0 + r];
      uk.u.x = kv.x; uk.u.y = kv.y; uk.u.z = kv.x; uk.u.w = kv.y;
    }
    U4H uv0, uv1;
    uv0.u = vb4[k0 + vbase];
    uv1.u = vb4[k0 + 16 + vbase];
    float16v st =
        __builtin_amdgcn_mfma_f32_32x32x16_f16(uk.h, uq.h, zero, 0, 0, 0);
#define PV_CHUNK(C, UV)                                                      \
  {                                                                          \
    union { uint u[4]; half8v h; } up;                                       \
    _Pragma("unroll")                                                        \
    for (int m = 0; m < 4; ++m) {                                            \
      union { fp16x2 f; uint u; } cv;                                        \
      cv.f = __builtin_amdgcn_cvt_pkrtz(st[8 * C + 2 * m],                   \
                                        st[8 * C + 2 * m + 1]);              \
      uint u2 = cv.u, p;                                                     \
      PKFMA(p, kC6, u2, kC5);                                                \
      PKFMA(p, p, u2, kC4);                                                  \
      PKFMA(p, p, u2, kC3);                                                  \
      PKFMA(p, p, u2, kC2);                                                  \
      PKFMA(p, p, u2, kC1);                                                  \
      PKFMA(p, p, u2, kC0);                                                  \
      up.u[m] = p;                                                           \
    }                                                                        \
    acc = __builtin_amdgcn_mfma_f32_32x32x16_f16(UV.h, up.h, acc, 0, 0, 0);  \
  }
    PV_CHUNK(0, uv0)
    PV_CHUNK(1, uv1)
#undef PV_CHUNK
  }

  float denom = __shfl_xor(acc[0], 32);  // lanes 0-31 get PV row 4 = sum P
  if (hi == 0) {
    float inv = 1.0f / denom;  // V unscaled: no extra factor
    union { fp16x2 p[2]; uint2 u; } res;
    res.p[0] = __builtin_amdgcn_cvt_pkrtz(acc[0] * inv, acc[1] * inv);
    res.p[1] = __builtin_amdgcn_cvt_pkrtz(acc[2] * inv, acc[3] * inv);
    int b = bh >> 5, head = bh & 31;
    o16u2[(((b << 10) + q0 + r) << 5) + head] = res.u;
  }
}

// ---------------------------------------------------------------------------
// K0: pack W into B-fragment layout wtb[e>>3][col][e&7] (f16) for the
// combine MFMA: B[k=e][col] = W[col][e].
// ---------------------------------------------------------------------------
__global__ __launch_bounds__(256) void wtb_kernel(
    const float* __restrict__ W, _Float16* __restrict__ wtb) {
  int i = blockIdx.x * 256 + threadIdx.x;  // 16384
  int col = i >> 7, e = i & 127;
  wtb[((e >> 3) << 10) + (col << 3) + (e & 7)] = (_Float16)W[i];
}

// ---------------------------------------------------------------------------
// K3: combine GEMM out[8192][128] = o16 @ W^T via mfma_f32_16x16x32_f16.
// One wave per 16x16 tile: 512 row-tiles x 8 col-tiles = 4096 waves.
// (verified R6/R8/R10/R11: ~3 us)
// ---------------------------------------------------------------------------
__global__ __launch_bounds__(256) void combine_kernel(
    const _Float16* __restrict__ o16, const _Float16* __restrict__ wtb,
    float* __restrict__ out) {
  const int lane = threadIdx.x & 63;
  const int wv = threadIdx.x >> 6;
  const int job = blockIdx.x * 4 + wv;  // 0..4095
  const int rt = job >> 3, ct = job & 7;
  const int c = lane & 15, g = lane >> 4;
  const uint4* a4 = (const uint4*)o16;
  const uint4* b4 = (const uint4*)wtb;
  const int arow = (rt << 4) + c;
  union U4H { uint4 u; half8v h; };
  float4v acc = {};
#pragma unroll
  for (int t = 0; t < 4; ++t) {
    U4H ua, ub;
    ua.u = a4[(arow << 4) + (t << 2) + g];
    ub.u = b4[(((t << 2) + g) << 7) + (ct << 4) + c];
    acc = __builtin_amdgcn_mfma_f32_16x16x32_f16(ua.h, ub.h, acc, 0, 0, 0);
  }
  const int orow = (rt << 4) + (g << 2);
  const int ocol = (ct << 4) + c;
#pragma unroll
  for (int reg = 0; reg < 4; ++reg)
    out[(orow + reg) * 128 + ocol] = acc[reg];
}

extern "C" void kernel_launch(void* const* d_in, const int* in_sizes, int n_in,
                              void* d_out, int out_size, void* d_ws,
                              size_t ws_size, hipStream_t stream) {
  const float* x = (const float*)d_in[0];   // [8,1024,128] f32
  const float* qp = (const float*)d_in[1];  // [1,4] f32
  const float* W = (const float*)d_in[2];   // [128,128] f32
  float* out = (float*)d_out;               // [8,1024,128] f32

  char* ws = (char*)d_ws;
  _Float16* h16 = (_Float16*)ws;                // [256][1024][4] f16 = 2 MB
  _Float16* hvq = (_Float16*)(ws + (2 << 20));  // [256][32][2][8][2][8] = 4 MB
  _Float16* o16 = (_Float16*)(ws + (6 << 20));  // [8192][128] f16 = 2 MB
  _Float16* wtb = (_Float16*)(ws + (8 << 20));  // [16][128][8] f16 = 32 KB

  wtb_kernel<<<64, 256, 0, stream>>>(W, wtb);
  qenc_kernel<<<1024, 256, 0, stream>>>((const float4*)x, qp, (uint2*)h16,
                                        (ushort*)hvq, (uint2*)hvq);
  attn_kernel<<<2048, 256, 0, stream>>>(h16, hvq, (uint2*)o16);
  combine_kernel<<<1024, 256, 0, stream>>>(o16, wtb, out);
}

// Round 14
// 53.647 us; speedup vs baseline: 1.4226x; 1.4226x over previous
//
#include <hip/hip_runtime.h>

// Problem constants: B=8, S=1024, E=128, H=32, DK=4.
constexpr int kS = 1024;

typedef __fp16 fp16x2 __attribute__((ext_vector_type(2)));
typedef _Float16 half4v __attribute__((ext_vector_type(4)));
typedef _Float16 half8v __attribute__((ext_vector_type(8)));
typedef float float4v __attribute__((ext_vector_type(4)));

// ---------------------------------------------------------------------------
// Feature-map attention (R14 rewrite): P[q,k] = e^{q.k/2}, q.k/2 in [-2,2].
// Deg-6 Chebyshev: e^s ~= sum_n b_n s^n (abs err ~4.5e-4) ->
// P = sum_alpha w_a m_q^a m_k^a over 210 monomials (|a|<=6 in 4 vars),
// w_a = b_n * n!/(2^n * a0!a1!a2!a3!).  Attention = two rank-210 contractions:
//   M[a][c] = sum_k m_k[a]*vv_k[c]  (vv = [z,1]; col 4 = softmax denominator)
//   num[q][c] = sum_a (w_a m_q[a]) * M[a][c];  out = num[0..3]/num[4].
// ---------------------------------------------------------------------------

// deg-6 power-basis coeffs of the Chebyshev approx of e^s on [-2,2],
// derived from Bessel I_n(2) (truncation err ~4.5e-4 abs).
__device__ __forceinline__ float wcoef(int a0, int a1, int a2, int a3) {
  const float b[7] = {1.0000101f, 1.0010454f, 0.5001437f, 0.1641115f,
                      0.0413223f, 0.00972570f, 0.00156770f};
  const float f[7] = {1.f, 1.f, 2.f, 6.f, 24.f, 120.f, 720.f};
  const float p2[7] = {1.f, 2.f, 4.f, 8.f, 16.f, 32.f, 64.f};
  int n = a0 + a1 + a2 + a3;
  return b[n] * f[n] / (p2[n] * f[a0] * f[a1] * f[a2] * f[a3]);
}

// Canonical graded enumeration of the 210 monomials. ALL kernels use this
// one generator so indices agree. Fully unrolled: idx and exponents become
// compile-time constants; running products cost ~1.2 mul per monomial.
template <class F>
__device__ __forceinline__ void for_each_mono(float z0, float z1, float z2,
                                              float z3, F&& f) {
  int idx = 0;
  float p0 = 1.f;
#pragma unroll
  for (int a0 = 0; a0 <= 6; ++a0) {
    float p1 = p0;
#pragma unroll
    for (int a1 = 0; a1 <= 6 - a0; ++a1) {
      float p2 = p1;
#pragma unroll
      for (int a2 = 0; a2 <= 6 - a0 - a1; ++a2) {
        float p3 = p2;
#pragma unroll
        for (int a3 = 0; a3 <= 6 - a0 - a1 - a2; ++a3) {
          f(idx, p3, a0, a1, a2, a3);
          ++idx;
          p3 *= z3;
        }
        p2 *= z2;
      }
      p1 *= z1;
    }
    p0 *= z0;
  }
}

// ---------------------------------------------------------------------------
// K1: quantum encoder (analytic collapse, verified R1-R13).
// z0=c1c2c3, z1=c0c1, z2=c0c1c2, z3=c0c1c2c3, c_w=cos(x_w+theta_w).
// h16[bh][s][d] = f16(z_d), UNSCALED (feature kernels read z directly).
// ---------------------------------------------------------------------------
__global__ __launch_bounds__(256) void qenc_kernel(
    const float4* __restrict__ x4, const float* __restrict__ qp,
    uint2* __restrict__ h16u) {
  int idx = blockIdx.x * 256 + threadIdx.x;
  float4 a = x4[idx];
  float c0 = cosf(a.x + qp[0]);
  float c1 = cosf(a.y + qp[1]);
  float c2 = cosf(a.z + qp[2]);
  float c3 = cosf(a.w + qp[3]);
  float z1 = c0 * c1;
  float z2 = z1 * c2;
  float z3 = z2 * c3;
  float z0 = c1 * c2 * c3;
  union { half4v h; uint2 u; } z;
  z.h.x = (_Float16)z0;
  z.h.y = (_Float16)z1;
  z.h.z = (_Float16)z2;
  z.h.w = (_Float16)z3;
  int b = idx >> 15;
  int s = (idx >> 5) & (kS - 1);
  int head = idx & 31;
  int bh = b * 32 + head;
  h16u[(bh << 10) + s] = z.u;
}

// ---------------------------------------------------------------------------
// K2a: M[bh][half][alpha][c] partials. Block = (bh, half of 512 keys),
// 4 chunks of 128 keys. Phase1: 2 threads/token compute monomials (split at
// alpha 105; wave-uniform predicate) into LDS sm (pad 134 -> <=2-way banks).
// Phase2: thread alpha contracts sm row with vv (uniform b128 broadcast).
// No atomics; every LDS/global byte read is written first (R12 lesson).
// ---------------------------------------------------------------------------
__global__ __launch_bounds__(256) void featM_kernel(
    const _Float16* __restrict__ h16, float* __restrict__ Mpart) {
  __shared__ _Float16 sm[210][134];
  __shared__ float vv[128][4];
  const int bh = blockIdx.x >> 1;
  const int half = blockIdx.x & 1;
  const int t = threadIdx.x;
  const bool hiH = t >= 128;
  const int tok = hiH ? t - 128 : t;
  const uint2* __restrict__ hb = (const uint2*)(h16) + (bh << 10) + (half << 9);

  float acc0 = 0.f, acc1 = 0.f, acc2 = 0.f, acc3 = 0.f, acc4 = 0.f;

  for (int ch = 0; ch < 4; ++ch) {
    // phase 1: features for this chunk's 128 tokens
    {
      union { uint2 u; half4v h; } uz;
      uz.u = hb[(ch << 7) + tok];
      float z0 = (float)uz.h.x, z1 = (float)uz.h.y;
      float z2 = (float)uz.h.z, z3 = (float)uz.h.w;
      if (!hiH) {
        vv[tok][0] = z0; vv[tok][1] = z1; vv[tok][2] = z2; vv[tok][3] = z3;
      }
      for_each_mono(z0, z1, z2, z3,
                    [&](int mi, float m, int, int, int, int) {
                      if (hiH ? (mi >= 105) : (mi < 105))
                        sm[mi][tok] = (_Float16)m;
                    });
    }
    __syncthreads();
    // phase 2: M += sm-row . [vv,1]
    if (t < 210) {
      for (int k = 0; k < 128; ++k) {
        float m = (float)sm[t][k];
        float4 v = *(const float4*)vv[k];  // uniform -> broadcast
        acc0 += m * v.x; acc1 += m * v.y;
        acc2 += m * v.z; acc3 += m * v.w;
        acc4 += m;
      }
    }
    __syncthreads();
  }
  if (t < 210) {
    float* mp = Mpart + (((bh << 1) + half) * 210 + t) * 5;
    mp[0] = acc0; mp[1] = acc1; mp[2] = acc2; mp[3] = acc3; mp[4] = acc4;
  }
}

// ---------------------------------------------------------------------------
// K2b: out_num[q] = (w o m_q) . M ; out = num/den. Block = (bh, q-chunk 256).
// Prologue reduces the 2 half-partials into LDS Mw[210][8] (b128-aligned).
// Main loop: unrolled 210-term contraction; w folds to compile-time literals.
// ---------------------------------------------------------------------------
__global__ __launch_bounds__(256) void featC_kernel(
    const _Float16* __restrict__ h16, const float* __restrict__ Mpart,
    uint2* __restrict__ o16u2) {
  __shared__ float Mw[210][8];
  const int bh = blockIdx.x >> 2;
  const int qc = blockIdx.x & 3;
  const int t = threadIdx.x;
  if (t < 210) {
    const float* m0 = Mpart + ((bh << 1) * 210 + t) * 5;
    const float* m1 = m0 + 210 * 5;
#pragma unroll
    for (int c = 0; c < 5; ++c) Mw[t][c] = m0[c] + m1[c];
  }
  __syncthreads();

  const int q = (qc << 8) + t;
  union { uint2 u; half4v h; } uz;
  uz.u = ((const uint2*)h16)[(bh << 10) + q];
  float z0 = (float)uz.h.x, z1 = (float)uz.h.y;
  float z2 = (float)uz.h.z, z3 = (float)uz.h.w;

  float n0 = 0.f, n1 = 0.f, n2 = 0.f, n3 = 0.f, den = 0.f;
  for_each_mono(z0, z1, z2, z3,
                [&](int mi, float m, int a0, int a1, int a2, int a3) {
                  float wm = m * wcoef(a0, a1, a2, a3);  // literal after unroll
                  float4 M4 = *(const float4*)&Mw[mi][0];
                  n0 += wm * M4.x; n1 += wm * M4.y;
                  n2 += wm * M4.z; n3 += wm * M4.w;
                  den += wm * Mw[mi][4];
                });

  float inv = 1.0f / den;
  union { fp16x2 p[2]; uint2 u; } res;
  res.p[0] = __builtin_amdgcn_cvt_pkrtz(n0 * inv, n1 * inv);
  res.p[1] = __builtin_amdgcn_cvt_pkrtz(n2 * inv, n3 * inv);
  int b = bh >> 5, head = bh & 31;
  o16u2[(((b << 10) + q) << 5) + head] = res.u;
}

// ---------------------------------------------------------------------------
// K0: pack W into B-fragment layout wtb[e>>3][col][e&7] (f16) for the
// combine MFMA: B[k=e][col] = W[col][e].
// ---------------------------------------------------------------------------
__global__ __launch_bounds__(256) void wtb_kernel(
    const float* __restrict__ W, _Float16* __restrict__ wtb) {
  int i = blockIdx.x * 256 + threadIdx.x;  // 16384
  int col = i >> 7, e = i & 127;
  wtb[((e >> 3) << 10) + (col << 3) + (e & 7)] = (_Float16)W[i];
}

// ---------------------------------------------------------------------------
// K3: combine GEMM out[8192][128] = o16 @ W^T via mfma_f32_16x16x32_f16.
// One wave per 16x16 tile. (verified R6-R13: ~3 us)
// ---------------------------------------------------------------------------
__global__ __launch_bounds__(256) void combine_kernel(
    const _Float16* __restrict__ o16, const _Float16* __restrict__ wtb,
    float* __restrict__ out) {
  const int lane = threadIdx.x & 63;
  const int wv = threadIdx.x >> 6;
  const int job = blockIdx.x * 4 + wv;  // 0..4095
  const int rt = job >> 3, ct = job & 7;
  const int c = lane & 15, g = lane >> 4;
  const uint4* a4 = (const uint4*)o16;
  const uint4* b4 = (const uint4*)wtb;
  const int arow = (rt << 4) + c;
  union U4H { uint4 u; half8v h; };
  float4v acc = {};
#pragma unroll
  for (int t = 0; t < 4; ++t) {
    U4H ua, ub;
    ua.u = a4[(arow << 4) + (t << 2) + g];
    ub.u = b4[(((t << 2) + g) << 7) + (ct << 4) + c];
    acc = __builtin_amdgcn_mfma_f32_16x16x32_f16(ua.h, ub.h, acc, 0, 0, 0);
  }
  const int orow = (rt << 4) + (g << 2);
  const int ocol = (ct << 4) + c;
#pragma unroll
  for (int reg = 0; reg < 4; ++reg)
    out[(orow + reg) * 128 + ocol] = acc[reg];
}

extern "C" void kernel_launch(void* const* d_in, const int* in_sizes, int n_in,
                              void* d_out, int out_size, void* d_ws,
                              size_t ws_size, hipStream_t stream) {
  const float* x = (const float*)d_in[0];   // [8,1024,128] f32
  const float* qp = (const float*)d_in[1];  // [1,4] f32
  const float* W = (const float*)d_in[2];   // [128,128] f32
  float* out = (float*)d_out;               // [8,1024,128] f32

  char* ws = (char*)d_ws;
  _Float16* h16 = (_Float16*)ws;                 // [256][1024][4] f16 = 2 MB
  float* Mpart = (float*)(ws + (2 << 20));       // [256][2][210][5] f32 ~2.1MB
  _Float16* o16 = (_Float16*)(ws + (6 << 20));   // [8192][128] f16 = 2 MB
  _Float16* wtb = (_Float16*)(ws + (8 << 20));   // [16][128][8] f16 = 32 KB

  wtb_kernel<<<64, 256, 0, stream>>>(W, wtb);
  qenc_kernel<<<1024, 256, 0, stream>>>((const float4*)x, qp, (uint2*)h16);
  featM_kernel<<<512, 256, 0, stream>>>(h16, Mpart);
  featC_kernel<<<1024, 256, 0, stream>>>(h16, Mpart, (uint2*)o16);
  combine_kernel<<<1024, 256, 0, stream>>>(o16, wtb, out);
}